// Round 1
// baseline (3970.416 us; speedup 1.0000x reference)
//
#include <hip/hip_runtime.h>

#define TLEN  1024
#define HID   96
#define NGATE 384
#define NTHR  768

__device__ __forceinline__ float sigf(float x) {
    return 1.0f / (1.0f + __expf(-x));
}
__device__ __forceinline__ float tanh_fast(float x) {
    float e = __expf(2.0f * x);
    return 1.0f - 2.0f / (e + 1.0f);
}

extern "C" __global__ void __launch_bounds__(NTHR, 3)
lstm2_fused(const float* __restrict__ x,
            const float* __restrict__ Wih0, const float* __restrict__ Whh0,
            const float* __restrict__ bih0, const float* __restrict__ bhh0,
            const float* __restrict__ Wih1, const float* __restrict__ Whh1,
            const float* __restrict__ bih1, const float* __restrict__ bhh1,
            const float* __restrict__ Wl,   const float* __restrict__ bl,
            float* __restrict__ out)
{
    __shared__ __attribute__((aligned(16))) float x_s[TLEN];
    __shared__ __attribute__((aligned(16))) float h1_s[HID];
    __shared__ __attribute__((aligned(16))) float h2_s[HID];
    __shared__ __attribute__((aligned(16))) float g_s[NGATE];
    __shared__ __attribute__((aligned(16))) float po_s[HID];
    __shared__ __attribute__((aligned(16))) float out_s[TLEN];

    const int tid  = threadIdx.x;
    const int b    = blockIdx.x;
    const int j    = tid >> 1;   // gate row 0..383 (torch order: i,f,g,o)
    const int half = tid & 1;    // which half of the dot product this thread owns

    // Stage this batch's entire x sequence (I=1 -> 4 KiB)
    for (int i = tid; i < TLEN; i += NTHR) x_s[i] = x[b * TLEN + i];

    // ---- Register-resident weights ----
    // Phase A: thread (j,half) holds W_hh0[j][48*half .. 48*half+47]
    // Phase C: half==0 holds W_ih1[j][0..95], half==1 holds W_hh1[j][0..95]
    float4 w0[12];
    float4 w1[24];
    {
        const float4* p0 = reinterpret_cast<const float4*>(Whh0 + j * HID + 48 * half);
        #pragma unroll
        for (int k = 0; k < 12; ++k) w0[k] = p0[k];
        const float* m1 = half ? Whh1 : Wih1;
        const float4* p1 = reinterpret_cast<const float4*>(m1 + j * HID);
        #pragma unroll
        for (int k = 0; k < 24; ++k) w1[k] = p1[k];
    }
    const float bias0 = bih0[j] + bhh0[j];
    const float wx0   = Wih0[j];          // W_ih0 is [384,1]
    const float bias1 = bih1[j] + bhh1[j];
    const float wl_u  = (tid < HID) ? Wl[tid] : 0.0f;
    const float bl0   = bl[0];

    float c1 = 0.0f, c2 = 0.0f;
    if (tid < HID) { h1_s[tid] = 0.0f; h2_s[tid] = 0.0f; }
    __syncthreads();

    #pragma unroll 1
    for (int t = 0; t < TLEN; ++t) {
        // ---- A: layer-1 gates: g0[j] = bias0 + x_t*Wih0[j] + dot(Whh0[j], h1_prev)
        {
            const float4* hv = reinterpret_cast<const float4*>(h1_s + 48 * half);
            float4 a = make_float4(0.f, 0.f, 0.f, 0.f);
            #pragma unroll
            for (int k = 0; k < 12; ++k) {
                float4 h4 = hv[k];
                a.x = fmaf(w0[k].x, h4.x, a.x);
                a.y = fmaf(w0[k].y, h4.y, a.y);
                a.z = fmaf(w0[k].z, h4.z, a.z);
                a.w = fmaf(w0[k].w, h4.w, a.w);
            }
            float s = (a.x + a.y) + (a.z + a.w);
            s += __shfl_xor(s, 1);
            if (half == 0) g_s[j] = s + bias0 + wx0 * x_s[t];
        }
        __syncthreads();
        // ---- B: layer-1 pointwise (96 units)
        if (tid < HID) {
            float gi = g_s[tid];
            float gf = g_s[HID + tid];
            float gg = g_s[2 * HID + tid];
            float go = g_s[3 * HID + tid];
            c1 = sigf(gf) * c1 + sigf(gi) * tanh_fast(gg);
            h1_s[tid] = sigf(go) * tanh_fast(c1);
        }
        __syncthreads();
        // ---- C: layer-2 gates: g1[j] = bias1 + dot(Wih1[j], h1_t) + dot(Whh1[j], h2_prev)
        {
            const float4* hv = reinterpret_cast<const float4*>(half ? h2_s : h1_s);
            float4 a = make_float4(0.f, 0.f, 0.f, 0.f);
            #pragma unroll
            for (int k = 0; k < 24; ++k) {
                float4 h4 = hv[k];
                a.x = fmaf(w1[k].x, h4.x, a.x);
                a.y = fmaf(w1[k].y, h4.y, a.y);
                a.z = fmaf(w1[k].z, h4.z, a.z);
                a.w = fmaf(w1[k].w, h4.w, a.w);
            }
            float s = (a.x + a.y) + (a.z + a.w);
            s += __shfl_xor(s, 1);
            if (half == 0) g_s[j] = s + bias1;
        }
        __syncthreads();
        // ---- D: layer-2 pointwise + linear-head partials
        if (tid < HID) {
            float gi = g_s[tid];
            float gf = g_s[HID + tid];
            float gg = g_s[2 * HID + tid];
            float go = g_s[3 * HID + tid];
            c2 = sigf(gf) * c2 + sigf(gi) * tanh_fast(gg);
            float h2 = sigf(go) * tanh_fast(c2);
            h2_s[tid] = h2;
            po_s[tid] = wl_u * h2;
        }
        __syncthreads();
        // ---- E: out[b][t] = sum(po) + bl  (wave 0 only; no trailing barrier needed:
        //      next A never touches po_s/out_s, and 3 barriers sit before next D)
        if (tid < 64) {
            float v = po_s[tid] + ((tid < 32) ? po_s[64 + tid] : 0.0f);
            v += __shfl_xor(v, 32);
            v += __shfl_xor(v, 16);
            v += __shfl_xor(v, 8);
            v += __shfl_xor(v, 4);
            v += __shfl_xor(v, 2);
            v += __shfl_xor(v, 1);
            if (tid == 0) out_s[t] = v + bl0;
        }
    }
    __syncthreads();
    // coalesced final store: out is [B, T, 1]
    for (int i = tid; i < TLEN; i += NTHR) out[b * TLEN + i] = out_s[i];
}

extern "C" void kernel_launch(void* const* d_in, const int* in_sizes, int n_in,
                              void* d_out, int out_size, void* d_ws, size_t ws_size,
                              hipStream_t stream)
{
    (void)in_sizes; (void)n_in; (void)d_ws; (void)ws_size; (void)out_size;
    const float* x    = (const float*)d_in[0];
    const float* Wih0 = (const float*)d_in[1];
    const float* Whh0 = (const float*)d_in[2];
    const float* bih0 = (const float*)d_in[3];
    const float* bhh0 = (const float*)d_in[4];
    const float* Wih1 = (const float*)d_in[5];
    const float* Whh1 = (const float*)d_in[6];
    const float* bih1 = (const float*)d_in[7];
    const float* bhh1 = (const float*)d_in[8];
    const float* Wl   = (const float*)d_in[9];
    const float* bl   = (const float*)d_in[10];

    lstm2_fused<<<dim3(256), dim3(NTHR), 0, stream>>>(
        x, Wih0, Whh0, bih0, bhh0, Wih1, Whh1, bih1, bhh1, Wl, bl,
        (float*)d_out);
}

// Round 2
// 3214.705 us; speedup vs baseline: 1.2351x; 1.2351x over previous
//
#include <hip/hip_runtime.h>

#define TLEN  1024
#define HID   96
#define NGATE 384
#define NTHR  768
#define WSTR  12   // floats per thread kept in LDS (cols 84..95 of the phase-C row)

__device__ __forceinline__ float sigf(float x) {
    return 1.0f / (1.0f + __expf(-x));
}
__device__ __forceinline__ float tanh_fast(float x) {
    float e = __expf(2.0f * x);
    return 1.0f - 2.0f / (e + 1.0f);
}

// FMA a float4 of weights against a float4 of h (broadcast from LDS)
#define QFMA(W, HV, I)                                   \
    {                                                    \
        float4 h4 = (HV)[I];                             \
        acc.x = fmaf((W).x, h4.x, acc.x);                \
        acc.y = fmaf((W).y, h4.y, acc.y);                \
        acc.z = fmaf((W).z, h4.z, acc.z);                \
        acc.w = fmaf((W).w, h4.w, acc.w);                \
    }

extern "C" __global__ void __launch_bounds__(NTHR, 3)
lstm2_fused(const float* __restrict__ x,
            const float* __restrict__ Wih0, const float* __restrict__ Whh0,
            const float* __restrict__ bih0, const float* __restrict__ bhh0,
            const float* __restrict__ Wih1, const float* __restrict__ Whh1,
            const float* __restrict__ bih1, const float* __restrict__ bhh1,
            const float* __restrict__ Wl,   const float* __restrict__ bl,
            float* __restrict__ out)
{
    __shared__ __attribute__((aligned(16))) float x_s[TLEN];
    __shared__ __attribute__((aligned(16))) float out_s[TLEN];
    __shared__ __attribute__((aligned(16))) float g_s[NGATE];
    __shared__ __attribute__((aligned(16))) float h1_s[HID];
    __shared__ __attribute__((aligned(16))) float h2_s[HID];
    __shared__ __attribute__((aligned(16))) float po_s[HID];
    __shared__ __attribute__((aligned(16))) float wlds[NTHR * WSTR];  // 36 KB

    const int tid  = threadIdx.x;
    const int b    = blockIdx.x;
    const int j    = tid >> 1;   // gate row 0..383 (torch order i,f,g,o)
    const int half = tid & 1;

    // stage this batch's x sequence (I=1 -> 4 KiB)
    for (int i = tid; i < TLEN; i += NTHR) x_s[i] = x[b * TLEN + i];

    // ---- phase-A weights: Whh0[j][48*half .. +47], 12 NAMED float4s ----
    const float4* p0 = reinterpret_cast<const float4*>(Whh0 + j * HID + 48 * half);
    float4 a0 = p0[0],  a1 = p0[1],  a2 = p0[2],  a3 = p0[3];
    float4 a4 = p0[4],  a5 = p0[5],  a6 = p0[6],  a7 = p0[7];
    float4 a8 = p0[8],  a9 = p0[9],  a10 = p0[10], a11 = p0[11];

    // ---- phase-C weights: row j of (half ? Whh1 : Wih1) ----
    // cols 0..83 in 21 NAMED float4s; cols 84..95 (3 float4s) go to LDS
    const float* m1 = half ? Whh1 : Wih1;
    const float4* p1 = reinterpret_cast<const float4*>(m1 + j * HID);
    float4 b0 = p1[0],  b1 = p1[1],  b2 = p1[2],  b3 = p1[3];
    float4 b4 = p1[4],  b5 = p1[5],  b6 = p1[6],  b7 = p1[7];
    float4 b8 = p1[8],  b9 = p1[9],  b10 = p1[10], b11 = p1[11];
    float4 b12 = p1[12], b13 = p1[13], b14 = p1[14], b15 = p1[15];
    float4 b16 = p1[16], b17 = p1[17], b18 = p1[18], b19 = p1[19];
    float4 b20 = p1[20];
    {
        float4* wl = reinterpret_cast<float4*>(wlds + tid * WSTR);
        wl[0] = p1[21]; wl[1] = p1[22]; wl[2] = p1[23];
    }

    const float bias0 = bih0[j] + bhh0[j];
    const float wx0   = Wih0[j];              // W_ih0 is [384,1]
    const float bias1 = bih1[j] + bhh1[j];
    const float wl_u  = (tid < HID) ? Wl[tid] : 0.0f;
    const float bl0   = bl[0];

    float c1 = 0.0f, c2 = 0.0f;
    if (tid < HID) { h1_s[tid] = 0.0f; h2_s[tid] = 0.0f; }
    __syncthreads();

    #pragma unroll 1
    for (int t = 0; t < TLEN; ++t) {
        // ---- A: g0[j] = bias0 + x_t*Wih0[j] + dot(Whh0[j], h1_prev) ----
        {
            const float4* hA = reinterpret_cast<const float4*>(h1_s + 48 * half);
            float4 acc = make_float4(0.f, 0.f, 0.f, 0.f);
            QFMA(a0, hA, 0)  QFMA(a1, hA, 1)  QFMA(a2, hA, 2)  QFMA(a3, hA, 3)
            QFMA(a4, hA, 4)  QFMA(a5, hA, 5)  QFMA(a6, hA, 6)  QFMA(a7, hA, 7)
            QFMA(a8, hA, 8)  QFMA(a9, hA, 9)  QFMA(a10, hA, 10) QFMA(a11, hA, 11)
            float s = (acc.x + acc.y) + (acc.z + acc.w);
            s += __shfl_xor(s, 1);
            if (half == 0) g_s[j] = s + bias0 + wx0 * x_s[t];
        }
        __syncthreads();
        // ---- B: layer-1 pointwise (96 units) ----
        if (tid < HID) {
            float gi = g_s[tid];
            float gf = g_s[HID + tid];
            float gg = g_s[2 * HID + tid];
            float go = g_s[3 * HID + tid];
            c1 = sigf(gf) * c1 + sigf(gi) * tanh_fast(gg);
            h1_s[tid] = sigf(go) * tanh_fast(c1);
        }
        __syncthreads();
        // ---- C: g1[j] = bias1 + dot(Wih1[j], h1_t) + dot(Whh1[j], h2_prev) ----
        {
            const float4* hC = reinterpret_cast<const float4*>(half ? h2_s : h1_s);
            float4 acc = make_float4(0.f, 0.f, 0.f, 0.f);
            QFMA(b0, hC, 0)   QFMA(b1, hC, 1)   QFMA(b2, hC, 2)   QFMA(b3, hC, 3)
            QFMA(b4, hC, 4)   QFMA(b5, hC, 5)   QFMA(b6, hC, 6)   QFMA(b7, hC, 7)
            QFMA(b8, hC, 8)   QFMA(b9, hC, 9)   QFMA(b10, hC, 10) QFMA(b11, hC, 11)
            QFMA(b12, hC, 12) QFMA(b13, hC, 13) QFMA(b14, hC, 14) QFMA(b15, hC, 15)
            QFMA(b16, hC, 16) QFMA(b17, hC, 17) QFMA(b18, hC, 18) QFMA(b19, hC, 19)
            QFMA(b20, hC, 20)
            // tail cols 84..95 from LDS; opaque zero keeps these reads inside the
            // loop (otherwise LICM hoists 12 loop-invariant floats back into VGPRs)
            int zr;
            asm volatile("v_mov_b32 %0, 0" : "=v"(zr));
            const float4* wl = reinterpret_cast<const float4*>(wlds + tid * WSTR + zr);
            {
                float4 w = wl[0];
                float4 h4 = hC[21];
                acc.x = fmaf(w.x, h4.x, acc.x); acc.y = fmaf(w.y, h4.y, acc.y);
                acc.z = fmaf(w.z, h4.z, acc.z); acc.w = fmaf(w.w, h4.w, acc.w);
            }
            {
                float4 w = wl[1];
                float4 h4 = hC[22];
                acc.x = fmaf(w.x, h4.x, acc.x); acc.y = fmaf(w.y, h4.y, acc.y);
                acc.z = fmaf(w.z, h4.z, acc.z); acc.w = fmaf(w.w, h4.w, acc.w);
            }
            {
                float4 w = wl[2];
                float4 h4 = hC[23];
                acc.x = fmaf(w.x, h4.x, acc.x); acc.y = fmaf(w.y, h4.y, acc.y);
                acc.z = fmaf(w.z, h4.z, acc.z); acc.w = fmaf(w.w, h4.w, acc.w);
            }
            float s = (acc.x + acc.y) + (acc.z + acc.w);
            s += __shfl_xor(s, 1);
            if (half == 0) g_s[j] = s + bias1;
        }
        __syncthreads();
        // ---- D: layer-2 pointwise + linear-head partials ----
        if (tid < HID) {
            float gi = g_s[tid];
            float gf = g_s[HID + tid];
            float gg = g_s[2 * HID + tid];
            float go = g_s[3 * HID + tid];
            c2 = sigf(gf) * c2 + sigf(gi) * tanh_fast(gg);
            float h2 = sigf(go) * tanh_fast(c2);
            h2_s[tid] = h2;
            po_s[tid] = wl_u * h2;
        }
        __syncthreads();
        // ---- E: out[b][t] = sum(po) + bl (wave 0; no trailing barrier needed) ----
        if (tid < 64) {
            float v = po_s[tid] + ((tid < 32) ? po_s[64 + tid] : 0.0f);
            v += __shfl_xor(v, 32);
            v += __shfl_xor(v, 16);
            v += __shfl_xor(v, 8);
            v += __shfl_xor(v, 4);
            v += __shfl_xor(v, 2);
            v += __shfl_xor(v, 1);
            if (tid == 0) out_s[t] = v + bl0;
        }
    }
    __syncthreads();
    for (int i = tid; i < TLEN; i += NTHR) out[b * TLEN + i] = out_s[i];
}

extern "C" void kernel_launch(void* const* d_in, const int* in_sizes, int n_in,
                              void* d_out, int out_size, void* d_ws, size_t ws_size,
                              hipStream_t stream)
{
    (void)in_sizes; (void)n_in; (void)d_ws; (void)ws_size; (void)out_size;
    const float* x    = (const float*)d_in[0];
    const float* Wih0 = (const float*)d_in[1];
    const float* Whh0 = (const float*)d_in[2];
    const float* bih0 = (const float*)d_in[3];
    const float* bhh0 = (const float*)d_in[4];
    const float* Wih1 = (const float*)d_in[5];
    const float* Whh1 = (const float*)d_in[6];
    const float* bih1 = (const float*)d_in[7];
    const float* bhh1 = (const float*)d_in[8];
    const float* Wl   = (const float*)d_in[9];
    const float* bl   = (const float*)d_in[10];

    lstm2_fused<<<dim3(256), dim3(NTHR), 0, stream>>>(
        x, Wih0, Whh0, bih0, bhh0, Wih1, Whh1, bih1, bhh1, Wl, bl,
        (float*)d_out);
}